// Round 2
// baseline (760.853 us; speedup 1.0000x reference)
//
#include <hip/hip_runtime.h>
#include <hip/hip_bf16.h>
#include <cstdint>
#include <cstddef>

#define BB 32
#define NN 256
#define MM 256
#define DD 512
#define NEGF (-1e9f)
#define VSTR 264
#define NDIAG 513

__device__ __forceinline__ float softplus_f(float x) {
  return fmaxf(x, 0.f) + __logf(1.f + __expf(-fabsf(x)));
}
__device__ __forceinline__ float logsig_f(float x) {
  return fminf(x, 0.f) - __logf(1.f + __expf(-fabsf(x)));
}

// ---------------- GEMM + activation ----------------
// out[b][i][j] = act( dot(X[b][i][:], Y[b][j][:]) ), X,Y: [B][256][512] fp32
template<int OP>
__global__ __launch_bounds__(256) void gemm_act(const float* __restrict__ X,
                                                const float* __restrict__ Y,
                                                float* __restrict__ out) {
  const int b  = blockIdx.z;
  const int m0 = blockIdx.y * 64;
  const int n0 = blockIdx.x * 64;
  const float* Xb = X + (size_t)b * NN * DD;
  const float* Yb = Y + (size_t)b * MM * DD;

  __shared__ float xs[16][68];
  __shared__ float ys[16][68];

  const int t  = threadIdx.x;
  const int tm = t >> 4;        // 0..15
  const int tn = t & 15;        // 0..15
  const int lr = t >> 2;        // 0..63 (row within tile for loads)
  const int lk = (t & 3) << 2;  // 0,4,8,12 (k offset for float4 load)

  float acc[4][4];
  #pragma unroll
  for (int a = 0; a < 4; ++a)
    #pragma unroll
    for (int c = 0; c < 4; ++c) acc[a][c] = 0.f;

  for (int k0 = 0; k0 < DD; k0 += 16) {
    float4 xv = *(const float4*)(Xb + (size_t)(m0 + lr) * DD + k0 + lk);
    float4 yv = *(const float4*)(Yb + (size_t)(n0 + lr) * DD + k0 + lk);
    __syncthreads();  // protect previous iteration's LDS reads
    xs[lk + 0][lr] = xv.x; xs[lk + 1][lr] = xv.y;
    xs[lk + 2][lr] = xv.z; xs[lk + 3][lr] = xv.w;
    ys[lk + 0][lr] = yv.x; ys[lk + 1][lr] = yv.y;
    ys[lk + 2][lr] = yv.z; ys[lk + 3][lr] = yv.w;
    __syncthreads();
    #pragma unroll
    for (int kk = 0; kk < 16; ++kk) {
      float4 xr = *(const float4*)&xs[kk][tm << 2];
      float4 yr = *(const float4*)&ys[kk][tn << 2];
      float xa[4] = {xr.x, xr.y, xr.z, xr.w};
      float ya[4] = {yr.x, yr.y, yr.z, yr.w};
      #pragma unroll
      for (int a = 0; a < 4; ++a)
        #pragma unroll
        for (int c = 0; c < 4; ++c)
          acc[a][c] = fmaf(xa[a], ya[c], acc[a][c]);
    }
  }

  #pragma unroll
  for (int a = 0; a < 4; ++a) {
    float4 o;
    float* po = (float*)&o;
    #pragma unroll
    for (int c = 0; c < 4; ++c) {
      const float v = acc[a][c];
      po[c] = (OP == 0) ? softplus_f(v) : logsig_f(v);
    }
    *(float4*)(out + (size_t)b * NN * MM
                   + (size_t)(m0 + (tm << 2) + a) * MM + n0 + (tn << 2)) = o;
  }
}

// ---------------- soft-NW forward + backward DP ----------------
// V grid (N+1)x(M+1), diagonal storage Vg[d][i] = V[i][d-i], d=0..512, i=0..256.
// Thread t owns grid-row i = t+1 on every anti-diagonal.

struct BwL {
  float v_c, v_u1, v_d2, v_l1, th_u, a_u, th_d, th_l, a_l;
};

__device__ __forceinline__ BwL load_bw(int s, int i,
                                       const float* __restrict__ TH,
                                       const float* __restrict__ AM,
                                       const float* __restrict__ Vg) {
  BwL r;
  r.v_c = r.v_u1 = r.v_d2 = r.v_l1 = 0.f;
  r.th_u = r.a_u = r.th_d = r.th_l = r.a_l = 0.f;
  const int j = s - i;
  const bool valid = (i <= s - 1) && (i >= s - 256);
  if (valid) {
    const bool cu = (i <= 255);                 // consumer (i+1, j)
    const bool cd = (i <= 255) && (j <= 255);   // consumer (i+1, j+1)
    const bool cl = (j <= 255);                 // consumer (i, j+1)
    r.v_c = Vg[(size_t)s * VSTR + i];
    if (cu) {
      r.v_u1 = Vg[(size_t)(s + 1) * VSTR + (i + 1)];
      r.th_u = TH[i * MM + (j - 1)];
      r.a_u  = AM[i * MM + (j - 1)];
    }
    if (cd) {
      r.v_d2 = Vg[(size_t)(s + 2) * VSTR + (i + 1)];
      r.th_d = TH[i * MM + j];
    }
    if (cl) {
      r.v_l1 = Vg[(size_t)(s + 1) * VSTR + i];
      r.th_l = TH[(i - 1) * MM + j];
      r.a_l  = AM[(i - 1) * MM + j];
    }
  }
  return r;
}

__global__ __launch_bounds__(256) void nw_dp(const float* __restrict__ theta,
                                             const float* __restrict__ Amat,
                                             float* __restrict__ aln,
                                             float* __restrict__ ws) {
  const int b = blockIdx.x;
  const int t = threadIdx.x;   // 0..255
  const int i = t + 1;         // grid row 1..256
  const float* TH  = theta + (size_t)b * NN * MM;
  const float* AM  = Amat  + (size_t)b * NN * MM;
  float*       ALN = aln   + (size_t)b * NN * MM;
  float*       Vg  = ws    + (size_t)b * (NDIAG * VSTR);

  __shared__ float buf[3][VSTR];  // ring of last 3 diagonals (V in fwd, E in bwd)
  for (int k = t; k < 3 * VSTR; k += 256) ((float*)buf)[k] = NEGF;
  __syncthreads();
  if (t == 0) buf[0][0] = 0.f;    // V[0][0] = 0
  __syncthreads();

  // ---------- forward ----------
  float th_c = 0.f, a_c = 0.f;
  {
    const int d = 2;
    if ((i <= d - 1) && (i >= d - 256)) {
      th_c = TH[t * MM + (d - i - 1)];
      a_c  = AM[t * MM + (d - i - 1)];
    }
  }
  for (int d = 2; d <= 512; ++d) {
    // prefetch theta/A for diagonal d+1
    float th_n = 0.f, a_n = 0.f;
    if (d < 512) {
      if ((i <= d) && (i >= d + 1 - 256)) {
        th_n = TH[t * MM + (d - i)];
        a_n  = AM[t * MM + (d - i)];
      }
    }
    const bool valid = (i <= d - 1) && (i >= d - 256);
    float v = NEGF;
    if (valid) {
      const float vu = buf[(d - 1) % 3][t];   // V[i-1][j]
      const float vd = buf[(d - 2) % 3][t];   // V[i-1][j-1]
      const float vl = buf[(d - 1) % 3][i];   // V[i][j-1]
      const float x0 = a_c + vu;
      const float x2 = a_c + vl;
      const float mx = fmaxf(fmaxf(x0, vd), x2);
      v = th_c + mx + __logf(__expf(x0 - mx) + __expf(vd - mx) + __expf(x2 - mx));
    }
    // writes go to buffer d%3 only; reads were from (d-1)%3, (d-2)%3 -> one barrier
    if (valid) {
      buf[d % 3][i] = v;
      Vg[(size_t)d * VSTR + i] = v;
    }
    if (d <= 256) {
      if (t == d - 1) buf[d % 3][d] = NEGF;  // V[d][0] border
      if (t == 255)   buf[d % 3][0] = NEGF;  // V[0][d] border
    }
    __syncthreads();
    th_c = th_n; a_c = a_n;
  }

  // ---------- backward (E = dV[N,M]/dtheta, diag-by-diag) ----------
  BwL c = load_bw(512, i, TH, AM, Vg);
  for (int s = 512; s >= 2; --s) {
    BwL nx;
    nx.v_c = nx.v_u1 = nx.v_d2 = nx.v_l1 = 0.f;
    nx.th_u = nx.a_u = nx.th_d = nx.th_l = nx.a_l = 0.f;
    if (s > 2) nx = load_bw(s - 1, i, TH, AM, Vg);

    const int j = s - i;
    const bool valid = (i <= s - 1) && (i >= s - 256);
    float E = 0.f;
    if (valid) {
      const bool cu = (i <= 255);
      const bool cd = (i <= 255) && (j <= 255);
      const bool cl = (j <= 255);
      if (cu) E += buf[(s + 1) % 3][i + 1] * __expf(c.a_u + c.th_u + c.v_c - c.v_u1);
      if (cd) E += buf[(s + 2) % 3][i + 1] * __expf(c.th_d + c.v_c - c.v_d2);
      if (cl) E += buf[(s + 1) % 3][i]     * __expf(c.a_l + c.th_l + c.v_c - c.v_l1);
      if (i == 256 && j == 256) E = 1.f;    // terminal seed
    }
    if (valid) {
      buf[s % 3][i] = E;
      ALN[t * MM + (j - 1)] = E;
    }
    __syncthreads();
    c = nx;
  }
}

// ---------------- launcher ----------------
extern "C" void kernel_launch(void* const* d_in, const int* in_sizes, int n_in,
                              void* d_out, int out_size, void* d_ws, size_t ws_size,
                              hipStream_t stream) {
  const float* zx = (const float*)d_in[0];
  const float* zy = (const float*)d_in[1];
  const float* gx = (const float*)d_in[2];
  const float* gy = (const float*)d_in[3];

  float* out   = (float*)d_out;
  float* aln   = out;                              // [B][N][M]
  float* theta = out + (size_t)BB * NN * MM;       // [B][N][M]
  float* Amat  = out + (size_t)2 * BB * NN * MM;   // [B][N][M]
  float* ws    = (float*)d_ws;                     // V in diagonal layout

  dim3 gg(MM / 64, NN / 64, BB);
  gemm_act<0><<<gg, 256, 0, stream>>>(zx, zy, theta);
  gemm_act<1><<<gg, 256, 0, stream>>>(gx, gy, Amat);
  nw_dp<<<BB, 256, 0, stream>>>(theta, Amat, aln, ws);
}

// Round 3
// 468.298 us; speedup vs baseline: 1.6247x; 1.6247x over previous
//
#include <hip/hip_runtime.h>
#include <hip/hip_bf16.h>
#include <cstdint>
#include <cstddef>

#define BB 32
#define NN 256
#define MM 256
#define DD 512
#define NEGF (-1e9f)
#define LOG2E 1.4426950408889634f
#define WARR 131328  // 513*256 floats, one (batch, diag-array) plane

__device__ __forceinline__ float softplus_f(float x) {
  return fmaxf(x, 0.f) + __logf(1.f + __expf(-fabsf(x)));
}
__device__ __forceinline__ float logsig_f(float x) {
  return fminf(x, 0.f) - __logf(1.f + __expf(-fabsf(x)));
}

// ---------------- GEMM + activation + diag-layout side store ----------------
// out[b][i][j] = act(dot(X[b][i][:], Y[b][j][:]))  (row-major, fp32, an output)
// diag[b][i+j+2][i] = act * log2(e)                (for the DP wavefront kernel)
template<int OP>
__global__ __launch_bounds__(256) void gemm_act(const float* __restrict__ X,
                                                const float* __restrict__ Y,
                                                float* __restrict__ out,
                                                float* __restrict__ diag) {
  const int b  = blockIdx.z;
  const int m0 = blockIdx.y * 64;
  const int n0 = blockIdx.x * 64;
  const float* Xb = X + (size_t)b * NN * DD;
  const float* Yb = Y + (size_t)b * MM * DD;
  float* diagb = diag + (size_t)b * WARR;

  __shared__ float xs[16][68];
  __shared__ float ys[16][68];

  const int t  = threadIdx.x;
  const int tm = t >> 4;
  const int tn = t & 15;
  const int lr = t >> 2;
  const int lk = (t & 3) << 2;

  float acc[4][4];
  #pragma unroll
  for (int a = 0; a < 4; ++a)
    #pragma unroll
    for (int c = 0; c < 4; ++c) acc[a][c] = 0.f;

  for (int k0 = 0; k0 < DD; k0 += 16) {
    float4 xv = *(const float4*)(Xb + (size_t)(m0 + lr) * DD + k0 + lk);
    float4 yv = *(const float4*)(Yb + (size_t)(n0 + lr) * DD + k0 + lk);
    __syncthreads();
    xs[lk + 0][lr] = xv.x; xs[lk + 1][lr] = xv.y;
    xs[lk + 2][lr] = xv.z; xs[lk + 3][lr] = xv.w;
    ys[lk + 0][lr] = yv.x; ys[lk + 1][lr] = yv.y;
    ys[lk + 2][lr] = yv.z; ys[lk + 3][lr] = yv.w;
    __syncthreads();
    #pragma unroll
    for (int kk = 0; kk < 16; ++kk) {
      float4 xr = *(const float4*)&xs[kk][tm << 2];
      float4 yr = *(const float4*)&ys[kk][tn << 2];
      float xa[4] = {xr.x, xr.y, xr.z, xr.w};
      float ya[4] = {yr.x, yr.y, yr.z, yr.w};
      #pragma unroll
      for (int a = 0; a < 4; ++a)
        #pragma unroll
        for (int c = 0; c < 4; ++c)
          acc[a][c] = fmaf(xa[a], ya[c], acc[a][c]);
    }
  }

  #pragma unroll
  for (int a = 0; a < 4; ++a) {
    const int row = m0 + (tm << 2) + a;
    float4 o;
    float* po = (float*)&o;
    #pragma unroll
    for (int c = 0; c < 4; ++c) {
      const float v = acc[a][c];
      const float act = (OP == 0) ? softplus_f(v) : logsig_f(v);
      po[c] = act;
      const int col = n0 + (tn << 2) + c;
      diagb[(size_t)(row + col + 2) * 256 + row] = act * LOG2E;
    }
    *(float4*)(out + (size_t)b * NN * MM + (size_t)row * MM + n0 + (tn << 2)) = o;
  }
}

// ---------------- wave-synchronous soft-NW fwd+bwd ----------------
// One 64-lane wave per batch; lane t owns grid rows 4t+1..4t+4.
// Forward: V rings in registers (base-2 domain), softmax weights Q1/Q2/Q3
// stored per cell in diag layout. Backward: E rings in registers, 3 FMAs/cell.
__global__ __launch_bounds__(64) void nw_wave(const float* __restrict__ thD,
                                              const float* __restrict__ aD,
                                              float* __restrict__ q1D,
                                              float* __restrict__ q2D,
                                              float* __restrict__ q3D,
                                              float* __restrict__ aln) {
  const int b = blockIdx.x;
  const int t = threadIdx.x;  // 0..63
  const float4* th4 = (const float4*)(thD + (size_t)b * WARR);
  const float4* a4  = (const float4*)(aD  + (size_t)b * WARR);
  float4* q14 = (float4*)(q1D + (size_t)b * WARR);
  float4* q24 = (float4*)(q2D + (size_t)b * WARR);
  float4* q34 = (float4*)(q3D + (size_t)b * WARR);
  float* ALN = aln + (size_t)b * NN * MM;

  const int i0 = 4 * t + 1;  // grid row of element k=0

  // ---------- forward ----------
  float vp[4], vp2[4];  // V on diag d-1 / d-2 for own rows
  #pragma unroll
  for (int k = 0; k < 4; ++k) { vp[k] = NEGF; vp2[k] = NEGF; }

  float4 thc = th4[2 * 64 + t], ac = a4[2 * 64 + t];
  float4 thn = th4[3 * 64 + t], an = a4[3 * 64 + t];

  for (int d = 2; d <= 512; ++d) {
    float4 thp = make_float4(0.f, 0.f, 0.f, 0.f), ap = thp;
    if (d + 2 <= 512) { thp = th4[(d + 2) * 64 + t]; ap = a4[(d + 2) * 64 + t]; }

    // lane-boundary values (row 4t) from lane t-1; lane 0 sees grid row 0 border
    float vu_in = __shfl_up(vp[3], 1);
    float vd_in = __shfl_up(vp2[3], 1);
    if (t == 0) { vu_in = NEGF; vd_in = (d == 2) ? 0.f : NEGF; }

    float vnew[4];
    float4 q1v, q2v, q3v;
    #pragma unroll
    for (int k = 0; k < 4; ++k) {
      const int i = i0 + k;
      const float vu = (k == 0) ? vu_in : vp[k - 1];   // V[i-1][j]   (diag d-1)
      const float vd = (k == 0) ? vd_in : vp2[k - 1];  // V[i-1][j-1] (diag d-2)
      const float vl = vp[k];                          // V[i][j-1]   (diag d-1)
      const float a  = ((const float*)&ac)[k];
      const float th = ((const float*)&thc)[k];
      const float x0 = a + vu;
      const float x2 = a + vl;
      const float mx = fmaxf(fmaxf(x0, vd), x2);
      const float e0 = __builtin_amdgcn_exp2f(x0 - mx);
      const float e1 = __builtin_amdgcn_exp2f(vd - mx);
      const float e2 = __builtin_amdgcn_exp2f(x2 - mx);
      const float Z  = e0 + e1 + e2;
      const float rz = __builtin_amdgcn_rcpf(Z);
      const float v  = th + mx + __builtin_amdgcn_logf(Z);  // log2
      const bool valid = (i <= d - 1) && (i >= d - 256);
      vnew[k] = valid ? v : NEGF;  // sanitize (also kills NaN from uninit slots)
      ((float*)&q1v)[k] = e0 * rz;
      ((float*)&q2v)[k] = e1 * rz;
      ((float*)&q3v)[k] = e2 * rz;
    }
    q14[d * 64 + t] = q1v;
    q24[d * 64 + t] = q2v;
    q34[d * 64 + t] = q3v;
    #pragma unroll
    for (int k = 0; k < 4; ++k) { vp2[k] = vp[k]; vp[k] = vnew[k]; }
    thc = thn; ac = an; thn = thp; an = ap;
  }

  // ---------- backward: E[i,j] = sum over consumers Q_c * E_c ----------
  float ep[4], ep2[4];  // E on diag s+1 / s+2
  #pragma unroll
  for (int k = 0; k < 4; ++k) { ep[k] = 0.f; ep2[k] = 0.f; }

  float4 z4 = make_float4(0.f, 0.f, 0.f, 0.f);
  float4 qA1 = z4, qA2 = z4, qA3 = z4;  // Q[s+1]
  float4 qB2 = z4;                      // Q2[s+2]
  // in-flight: pend1 = Q[512], pend0 = Q[511]
  float4 p1q1 = q14[512 * 64 + t], p1q2 = q24[512 * 64 + t], p1q3 = q34[512 * 64 + t];
  float4 p0q1 = q14[511 * 64 + t], p0q2 = q24[511 * 64 + t], p0q3 = q34[511 * 64 + t];

  for (int s = 512; s >= 2; --s) {
    // row 4t+5 values from lane t+1
    const float sh_e1 = __shfl_down(ep[0], 1);
    const float sh_e2 = __shfl_down(ep2[0], 1);
    const float sh_q1 = __shfl_down(((float*)&qA1)[0], 1);
    const float sh_q2 = __shfl_down(((float*)&qB2)[0], 1);

    float enew[4];
    #pragma unroll
    for (int k = 0; k < 4; ++k) {
      const int i = i0 + k;
      const int j = s - i;
      const bool cellv = (j >= 1) && (j <= 256);
      float q1u = (k < 3) ? ((float*)&qA1)[k + 1] : sh_q1;  // Q1 of (i+1, j)
      float q2d = (k < 3) ? ((float*)&qB2)[k + 1] : sh_q2;  // Q2 of (i+1, j+1)
      float q3l = ((float*)&qA3)[k];                        // Q3 of (i,   j+1)
      const float eu = (k < 3) ? ep[k + 1]  : sh_e1;
      const float ed = (k < 3) ? ep2[k + 1] : sh_e2;
      const float el = ep[k];
      q1u = (i <= 255)               ? q1u : 0.f;
      q2d = (i <= 255 && j <= 255)   ? q2d : 0.f;
      q3l = (j <= 255)               ? q3l : 0.f;
      float E = q1u * eu + q2d * ed + q3l * el;
      if (s == 512 && i == 256) E = 1.f;  // terminal seed at (256,256)
      E = cellv ? E : 0.f;
      enew[k] = E;
      if (cellv) ALN[(size_t)(i - 1) * MM + (j - 1)] = E;
    }
    #pragma unroll
    for (int k = 0; k < 4; ++k) { ep2[k] = ep[k]; ep[k] = enew[k]; }
    // rotate Q pipeline: qB2 <- Q2[s+1], qA <- Q[s], refill 3 steps ahead
    qB2 = qA2;
    qA1 = p1q1; qA2 = p1q2; qA3 = p1q3;
    p1q1 = p0q1; p1q2 = p0q2; p1q3 = p0q3;
    if (s - 2 >= 2) {
      p0q1 = q14[(s - 2) * 64 + t];
      p0q2 = q24[(s - 2) * 64 + t];
      p0q3 = q34[(s - 2) * 64 + t];
    }
  }
}

// ---------------- launcher ----------------
extern "C" void kernel_launch(void* const* d_in, const int* in_sizes, int n_in,
                              void* d_out, int out_size, void* d_ws, size_t ws_size,
                              hipStream_t stream) {
  const float* zx = (const float*)d_in[0];
  const float* zy = (const float*)d_in[1];
  const float* gx = (const float*)d_in[2];
  const float* gy = (const float*)d_in[3];

  float* out   = (float*)d_out;
  float* aln   = out;                              // [B][N][M]
  float* theta = out + (size_t)BB * NN * MM;       // [B][N][M]
  float* Amat  = out + (size_t)2 * BB * NN * MM;   // [B][N][M]

  float* ws    = (float*)d_ws;
  float* thD   = ws;                               // [B][513][256]
  float* aD    = ws + (size_t)32 * WARR;
  float* q1D   = ws + (size_t)64 * WARR;
  float* q2D   = ws + (size_t)96 * WARR;
  float* q3D   = ws + (size_t)128 * WARR;

  dim3 gg(MM / 64, NN / 64, BB);
  gemm_act<0><<<gg, 256, 0, stream>>>(zx, zy, theta, thD);
  gemm_act<1><<<gg, 256, 0, stream>>>(gx, gy, Amat, aD);
  nw_wave<<<BB, 64, 0, stream>>>(thD, aD, q1D, q2D, q3D, aln);
}

// Round 5
// 381.756 us; speedup vs baseline: 1.9930x; 1.2267x over previous
//
#include <hip/hip_runtime.h>
#include <hip/hip_bf16.h>
#include <hip/hip_fp16.h>
#include <cstdint>
#include <cstddef>

#define BB 32
#define NN 256
#define MM 256
#define DD 512
#define NEGF (-1e9f)
#define LOG2E 1.4426950408889634f
#define WARR 131328  // 513*256 floats: one (batch, diag-array) plane

typedef __fp16 h2 __attribute__((ext_vector_type(2)));

__device__ __forceinline__ uint32_t pack_q(float a, float b) {
  h2 r = __builtin_amdgcn_cvt_pkrtz(a, b);      // (q1,q3) -> 2x fp16
  return __builtin_bit_cast(uint32_t, r);
}
__device__ __forceinline__ float2 unpack_q(uint32_t u) {
  h2 r = __builtin_bit_cast(h2, u);
  return make_float2((float)r.x, (float)r.y);
}

__device__ __forceinline__ float softplus_f(float x) {
  return fmaxf(x, 0.f) + __logf(1.f + __expf(-fabsf(x)));
}
__device__ __forceinline__ float logsig_f(float x) {
  return fminf(x, 0.f) - __logf(1.f + __expf(-fabsf(x)));
}

// ---------------- GEMM + activation + diag-layout side store ----------------
template<int OP>
__global__ __launch_bounds__(256) void gemm_act(const float* __restrict__ X,
                                                const float* __restrict__ Y,
                                                float* __restrict__ out,
                                                float* __restrict__ diag) {
  const int b  = blockIdx.z;
  const int m0 = blockIdx.y * 64;
  const int n0 = blockIdx.x * 64;
  const float* Xb = X + (size_t)b * NN * DD;
  const float* Yb = Y + (size_t)b * MM * DD;
  float* diagb = diag + (size_t)b * WARR;

  __shared__ float xs[16][68];
  __shared__ float ys[16][68];

  const int t  = threadIdx.x;
  const int tm = t >> 4;
  const int tn = t & 15;
  const int lr = t >> 2;
  const int lk = (t & 3) << 2;

  float acc[4][4];
  #pragma unroll
  for (int a = 0; a < 4; ++a)
    #pragma unroll
    for (int c = 0; c < 4; ++c) acc[a][c] = 0.f;

  for (int k0 = 0; k0 < DD; k0 += 16) {
    float4 xv = *(const float4*)(Xb + (size_t)(m0 + lr) * DD + k0 + lk);
    float4 yv = *(const float4*)(Yb + (size_t)(n0 + lr) * DD + k0 + lk);
    __syncthreads();
    xs[lk + 0][lr] = xv.x; xs[lk + 1][lr] = xv.y;
    xs[lk + 2][lr] = xv.z; xs[lk + 3][lr] = xv.w;
    ys[lk + 0][lr] = yv.x; ys[lk + 1][lr] = yv.y;
    ys[lk + 2][lr] = yv.z; ys[lk + 3][lr] = yv.w;
    __syncthreads();
    #pragma unroll
    for (int kk = 0; kk < 16; ++kk) {
      float4 xr = *(const float4*)&xs[kk][tm << 2];
      float4 yr = *(const float4*)&ys[kk][tn << 2];
      float xa[4] = {xr.x, xr.y, xr.z, xr.w};
      float ya[4] = {yr.x, yr.y, yr.z, yr.w};
      #pragma unroll
      for (int a = 0; a < 4; ++a)
        #pragma unroll
        for (int c = 0; c < 4; ++c)
          acc[a][c] = fmaf(xa[a], ya[c], acc[a][c]);
    }
  }

  #pragma unroll
  for (int a = 0; a < 4; ++a) {
    const int row = m0 + (tm << 2) + a;
    float4 o;
    float* po = (float*)&o;
    #pragma unroll
    for (int c = 0; c < 4; ++c) {
      const float v = acc[a][c];
      const float act = (OP == 0) ? softplus_f(v) : logsig_f(v);
      po[c] = act;
      const int col = n0 + (tn << 2) + c;
      diagb[(size_t)(row + col + 2) * 256 + row] = act * LOG2E;  // base-2 domain
    }
    *(float4*)(out + (size_t)b * NN * MM + (size_t)row * MM + n0 + (tn << 2)) = o;
  }
}

// ---------------- wave-synchronous soft-NW fwd+bwd, depth-8 pipeline --------
// One 64-lane wave per batch; lane t owns grid rows 4t+1..4t+4.
__global__ __launch_bounds__(64) void nw_wave(const float* __restrict__ thD,
                                              const float* __restrict__ aD,
                                              uint4* __restrict__ qpD,
                                              float* __restrict__ aln) {
  const int b = blockIdx.x;
  const int t = threadIdx.x;  // 0..63
  const float4* th4 = (const float4*)(thD + (size_t)b * WARR);
  const float4* a4  = (const float4*)(aD  + (size_t)b * WARR);
  uint4* qp = qpD + (size_t)b * (513 * 64);
  float* ALN = aln + (size_t)b * NN * MM;
  const int i0 = 4 * t + 1;

  // ---------- forward ----------
  float vp[4], vp2[4];
  #pragma unroll
  for (int k = 0; k < 4; ++k) { vp[k] = NEGF; vp2[k] = NEGF; }

  float4 thb[8], ab[8];
  #pragma unroll
  for (int dd = 2; dd <= 9; ++dd) {
    thb[dd & 7] = th4[dd * 64 + t];
    ab[dd & 7]  = a4[dd * 64 + t];
  }

  for (int blk = 0; blk < 64; ++blk) {
    #pragma unroll
    for (int u = 0; u < 8; ++u) {
      const int d  = 2 + blk * 8 + u;      // 2..513 (513 fully masked)
      const int sl = (2 + u) & 7;          // compile-time slot: d & 7

      float vu_in = __shfl_up(vp[3], 1);
      float vd_in = __shfl_up(vp2[3], 1);
      if (t == 0) { vu_in = NEGF; vd_in = (d == 2) ? 0.f : NEGF; }

      const float4 thc = thb[sl];
      const float4 ac  = ab[sl];
      float vnew[4];
      uint32_t pk[4];
      #pragma unroll
      for (int k = 0; k < 4; ++k) {
        const int i = i0 + k;
        const float vu = (k == 0) ? vu_in : vp[k - 1];   // V[i-1][j]
        const float vd = (k == 0) ? vd_in : vp2[k - 1];  // V[i-1][j-1]
        const float vl = vp[k];                          // V[i][j-1]
        const float a  = ((const float*)&ac)[k];
        const float th = ((const float*)&thc)[k];
        const float x0 = a + vu;
        const float x2 = a + vl;
        const float mx = fmaxf(fmaxf(x0, vd), x2);
        const float e0 = __builtin_amdgcn_exp2f(x0 - mx);
        const float e1 = __builtin_amdgcn_exp2f(vd - mx);
        const float e2 = __builtin_amdgcn_exp2f(x2 - mx);
        const float Z  = e0 + e1 + e2;
        const float rz = __builtin_amdgcn_rcpf(Z);
        const float v  = th + mx + __builtin_amdgcn_logf(Z);
        const bool valid = (i <= d - 1) && (i >= d - 256);
        vnew[k] = valid ? v : NEGF;
        pk[k] = pack_q(e0 * rz, e2 * rz);  // (q1, q3); q2 = 1-q1-q3
      }
      if (d <= 512) qp[d * 64 + t] = make_uint4(pk[0], pk[1], pk[2], pk[3]);
      #pragma unroll
      for (int k = 0; k < 4; ++k) { vp2[k] = vp[k]; vp[k] = vnew[k]; }
      if (d + 8 <= 512) {                  // refill same slot, 8 diags ahead
        thb[sl] = th4[(d + 8) * 64 + t];
        ab[sl]  = a4[(d + 8) * 64 + t];
      }
    }
  }

  // ---------- backward: E[i,j] = sum over consumers Q_c * E_c ----------
  float ep[4], ep2[4];
  #pragma unroll
  for (int k = 0; k < 4; ++k) { ep[k] = 0.f; ep2[k] = 0.f; }

  uint4 qr[8];
  #pragma unroll
  for (int x = 0; x < 8; ++x) qr[x] = make_uint4(0, 0, 0, 0);
  #pragma unroll
  for (int dd = 509; dd <= 512; ++dd) qr[dd & 7] = qp[dd * 64 + t];

  for (int blk = 0; blk < 64; ++blk) {
    #pragma unroll
    for (int u = 0; u < 8; ++u) {
      const int s   = 513 - (blk * 8 + u);  // 513..2 (513 fully masked)
      const int slA = (514 - u) & 7;        // slot of diag s+1
      const int slB = (515 - u) & 7;        // slot of diag s+2
      const int slL = (508 - u) & 7;        // slot of diag s-5 (load target)

      const float sh_e1 = __shfl_down(ep[0], 1);
      const float sh_e2 = __shfl_down(ep2[0], 1);
      const uint4 qA = qr[slA];
      const uint4 qB = qr[slB];
      const uint32_t sh_qA = (uint32_t)__shfl_down((int)qA.x, 1);
      const uint32_t sh_qB = (uint32_t)__shfl_down((int)qB.x, 1);

      float enew[4];
      #pragma unroll
      for (int k = 0; k < 4; ++k) {
        const int i = i0 + k;
        const int j = s - i;
        const bool cellv = (j >= 1) && (j <= 256);
        const uint32_t quA = (k < 3) ? (&qA.x)[k + 1] : sh_qA;  // Q(s+1), row i+1
        const uint32_t quB = (k < 3) ? (&qB.x)[k + 1] : sh_qB;  // Q(s+2), row i+1
        const uint32_t qcA = (&qA.x)[k];                        // Q(s+1), row i
        const float2 fA = unpack_q(quA);  // q1 of (i+1, j)
        const float2 fB = unpack_q(quB);  // (q1,q3) of (i+1, j+1)
        const float2 fC = unpack_q(qcA);  // q3 of (i, j+1)
        float q1u = fA.x;
        float q2d = 1.f - fB.x - fB.y;
        float q3l = fC.y;
        const float eu = (k < 3) ? ep[k + 1]  : sh_e1;
        const float ed = (k < 3) ? ep2[k + 1] : sh_e2;
        const float el = ep[k];
        q1u = (i <= 255)             ? q1u : 0.f;
        q2d = (i <= 255 && j <= 255) ? q2d : 0.f;
        q3l = (j <= 255)             ? q3l : 0.f;
        float E = q1u * eu + q2d * ed + q3l * el;
        if (s == 512 && i == 256) E = 1.f;   // terminal seed
        E = cellv ? E : 0.f;
        enew[k] = E;
        if (cellv) ALN[(size_t)(i - 1) * MM + (j - 1)] = E;
      }
      #pragma unroll
      for (int k = 0; k < 4; ++k) { ep2[k] = ep[k]; ep[k] = enew[k]; }
      if (s - 5 >= 2) qr[slL] = qp[(s - 5) * 64 + t];
    }
  }
}

// ---------------- launcher ----------------
extern "C" void kernel_launch(void* const* d_in, const int* in_sizes, int n_in,
                              void* d_out, int out_size, void* d_ws, size_t ws_size,
                              hipStream_t stream) {
  const float* zx = (const float*)d_in[0];
  const float* zy = (const float*)d_in[1];
  const float* gx = (const float*)d_in[2];
  const float* gy = (const float*)d_in[3];

  float* out   = (float*)d_out;
  float* aln   = out;                              // [B][N][M]
  float* theta = out + (size_t)BB * NN * MM;       // [B][N][M]
  float* Amat  = out + (size_t)2 * BB * NN * MM;   // [B][N][M]

  float* ws  = (float*)d_ws;
  float* thD = ws;                                 // [B][513][256] f32
  float* aD  = ws + (size_t)BB * WARR;             // [B][513][256] f32
  uint4* qpD = (uint4*)(ws + (size_t)2 * BB * WARR);  // [B][513][64] uint4 (half2 x4)

  dim3 gg(MM / 64, NN / 64, BB);
  gemm_act<0><<<gg, 256, 0, stream>>>(zx, zy, theta, thD);
  gemm_act<1><<<gg, 256, 0, stream>>>(gx, gy, Amat, aD);
  nw_wave<<<BB, 64, 0, stream>>>(thD, aD, qpD, aln);
}